// Round 4
// baseline (1632.231 us; speedup 1.0000x reference)
//
#include <hip/hip_runtime.h>
#include <hip/hip_bf16.h>
#include <stdint.h>

// SNN forward (snntorch Leaky, subtract reset), T=1024 B=128 NIN=256 HID=1024.
// d_out: out_spikes [T,B,2] | hidden_spikes [T,B,HID] | mem2_f [B,2]
//
// Round-4: k_snn gather widened to ds_read_b64 (2 j per lane, plain row-major
// 128KB LDS tile, lane pair = (2*lane, 2*lane+1)), explicit 2-stage register
// pipeline to keep 8+ reads outstanding at 1 wave/SIMD. LDS instruction count
// halves vs round-3 (the measured bottleneck: b32 issue-limited at 44 B/cy).
// k_h2 (bit-exact butterfly tree) / k_pack / k_scan unchanged from round-3.

#define TT  1024
#define BB  128
#define NIN 256
#define HID 1024

#define OFF_HID  262144ULL
#define OFF_MEM2 134479872ULL

__global__ __launch_bounds__(256) void k_transpose(const float* __restrict__ W1,
                                                   float* __restrict__ W1T) {
    int idx = blockIdx.x * 256 + threadIdx.x;     // 262144 elements
    int j = idx & (HID - 1);
    int i = idx >> 10;
    W1T[(size_t)i * HID + j] = W1[(size_t)j * NIN + i];
}

__global__ __launch_bounds__(256) void k_pack(const float* __restrict__ x,
                                              unsigned int* __restrict__ cntArr,
                                              unsigned char* __restrict__ idxArr,
                                              int slots) {
    size_t tb = blockIdx.x;                       // T*B blocks, 256 threads = i
    int tid = threadIdx.x;
    int lane = tid & 63, w = tid >> 6;
    float v = x[tb * NIN + tid];
    bool act = v > 0.5f;
    unsigned long long m = __ballot(act);
    __shared__ unsigned int wc[4];
    __shared__ unsigned char sIdx[96];
    if (lane == 0) wc[w] = (unsigned int)__popcll(m);
    __syncthreads();
    unsigned int off = 0;
#pragma unroll
    for (int k = 0; k < 4; ++k) if (k < w) off += wc[k];
    unsigned int cnt = wc[0] + wc[1] + wc[2] + wc[3];
    unsigned int rank = off + (unsigned int)__popcll(m & ((1ull << lane) - 1));
    if (act && rank < (unsigned int)slots) sIdx[rank] = (unsigned char)tid;
    __syncthreads();
    if (tid * 4 < slots)
        ((unsigned int*)(idxArr + tb * (size_t)slots))[tid] = ((const unsigned int*)sIdx)[tid];
    if (tid == 0) cntArr[tb] = cnt;
}

// Workgroup = 4 waves = 4 b's sharing a 128-j chunk of W1T (128KB LDS, plain
// row-major [i][128j]; lane reads float2 at (i, 2*lane)). Grid = 32 bg x 8 jc
// = 256 wgs -> exactly 1 wg/CU.
__global__ __launch_bounds__(256) void k_snn(const float* __restrict__ W1T,
                                             const unsigned int* __restrict__ cntArr,
                                             const unsigned char* __restrict__ idxArr,
                                             const float* __restrict__ x,
                                             const float* __restrict__ b1,
                                             float* __restrict__ outHid,
                                             int slots) {
#pragma clang fp contract(off)
    const int jc   = blockIdx.x & 7;
    const int bg   = blockIdx.x >> 3;
    const int lane = threadIdx.x & 63;
    const int wave = threadIdx.x >> 6;
    const int b    = (bg << 2) + wave;
    const int j0   = (jc << 7) + (lane << 1);     // lane's pair: j0, j0+1

    __shared__ float2 sW[NIN * 64];               // 128 KB: [i][pair l]
    for (int p = threadIdx.x; p < NIN * 64; p += 256) {
        int i = p >> 6, l = p & 63;
        sW[p] = *reinterpret_cast<const float2*>(W1T + (size_t)i * HID + (jc << 7) + (l << 1));
    }
    __syncthreads();

    float mem0 = 0.0f, mem1 = 0.0f;
    const float bias0 = b1[j0];
    const float bias1 = b1[j0 + 1];
    const int   ub    = __builtin_amdgcn_readfirstlane(b);

    // prefetch t=0 index data
    unsigned int cnt_v  = cntArr[(size_t)ub];
    unsigned int vIdx_v = ((const unsigned int*)(idxArr + (size_t)ub * (size_t)slots))[lane & 31];

#define GATH(dst, dw, sh) dst = sW[(((dw) >> (sh)) & 255) * 64 + lane]

    for (int t = 0; t < TT; ++t) {
        unsigned int cnt  = (unsigned int)__builtin_amdgcn_readfirstlane((int)cnt_v);
        unsigned int vIdx = vIdx_v;

        // prefetch t+1 (clamped) — hides global latency under the gather
        int tn = (t + 1 < TT) ? t + 1 : t;
        size_t tbn = (size_t)tn * BB + ub;
        cnt_v  = cntArr[tbn];
        vIdx_v = ((const unsigned int*)(idxArr + tbn * (size_t)slots))[lane & 31];

        float h0 = bias0, h1 = bias1;
        unsigned int lim = cnt < (unsigned int)slots ? cnt : (unsigned int)slots;
        unsigned int kb = lim & ~7u;

        if (kb) {
            // 2-stage software pipeline: batch k+1's reads issue before batch
            // k's adds, keeping 8-16 ds_read_b64 outstanding per wave.
            unsigned int d0 = (unsigned int)__builtin_amdgcn_readlane((int)vIdx, 0);
            unsigned int d1 = (unsigned int)__builtin_amdgcn_readlane((int)vIdx, 1);
            float2 a0, a1, a2, a3, a4, a5, a6, a7;
            GATH(a0, d0, 0);  GATH(a1, d0, 8);  GATH(a2, d0, 16); GATH(a3, d0, 24);
            GATH(a4, d1, 0);  GATH(a5, d1, 8);  GATH(a6, d1, 16); GATH(a7, d1, 24);
            for (unsigned int kk = 8; kk < kb; kk += 8) {
                unsigned int e0 = (unsigned int)__builtin_amdgcn_readlane((int)vIdx, (int)(kk >> 2));
                unsigned int e1 = (unsigned int)__builtin_amdgcn_readlane((int)vIdx, (int)(kk >> 2) + 1);
                float2 c0, c1, c2, c3, c4, c5, c6, c7;
                GATH(c0, e0, 0);  GATH(c1, e0, 8);  GATH(c2, e0, 16); GATH(c3, e0, 24);
                GATH(c4, e1, 0);  GATH(c5, e1, 8);  GATH(c6, e1, 16); GATH(c7, e1, 24);
                h0 += a0.x; h1 += a0.y;           // ascending-i order
                h0 += a1.x; h1 += a1.y;
                h0 += a2.x; h1 += a2.y;
                h0 += a3.x; h1 += a3.y;
                h0 += a4.x; h1 += a4.y;
                h0 += a5.x; h1 += a5.y;
                h0 += a6.x; h1 += a6.y;
                h0 += a7.x; h1 += a7.y;
                a0 = c0; a1 = c1; a2 = c2; a3 = c3;
                a4 = c4; a5 = c5; a6 = c6; a7 = c7;
            }
            h0 += a0.x; h1 += a0.y;
            h0 += a1.x; h1 += a1.y;
            h0 += a2.x; h1 += a2.y;
            h0 += a3.x; h1 += a3.y;
            h0 += a4.x; h1 += a4.y;
            h0 += a5.x; h1 += a5.y;
            h0 += a6.x; h1 += a6.y;
            h0 += a7.x; h1 += a7.y;
        }
        for (unsigned int kk = kb; kk < lim; ++kk) {
            unsigned int d = (unsigned int)__builtin_amdgcn_readlane((int)vIdx, (int)(kk >> 2));
            float2 wv = sW[((d >> ((kk & 3) * 8)) & 255) * 64 + lane];
            h0 += wv.x; h1 += wv.y;
        }
        if (cnt > (unsigned int)slots) {          // ~never: overflow fallback
            const float* xr = x + ((size_t)t * BB + ub) * NIN;
            unsigned int skip = (unsigned int)slots;
            for (int w = 0; w < 4; ++w) {
                unsigned long long m = __ballot(xr[(w << 6) + lane] > 0.5f);
                unsigned int pc = (unsigned int)__popcll(m);
                if (skip >= pc) { skip -= pc; continue; }
                while (skip) { m &= m - 1; --skip; }
                while (m) {
                    int i = (w << 6) + __builtin_ctzll(m);
                    m &= m - 1;
                    float2 wv = sW[i * 64 + lane];
                    h0 += wv.x; h1 += wv.y;
                }
            }
        }

        // membrane update (np fp32 semantics: mul, add separate)
        float mm0 = 0.9f * mem0; mm0 = mm0 + h0;
        float spk0 = (mm0 - 1.0f > 0.0f) ? 1.0f : 0.0f;
        mm0 = mm0 - spk0; mem0 = mm0;
        float mm1 = 0.9f * mem1; mm1 = mm1 + h1;
        float spk1 = (mm1 - 1.0f > 0.0f) ? 1.0f : 0.0f;
        mm1 = mm1 - spk1; mem1 = mm1;

        *reinterpret_cast<float2*>(outHid + (size_t)t * (BB * HID) + (size_t)b * HID + j0) =
            make_float2(spk0, spk1);              // coalesced 512B/wave
    }
#undef GATH
}

// One wave per (t,b): bit-identical layer-2 tree to rounds 1-3:
// per chunk c (ascending 0..15): r = spk[c*64+lane]*W2[o][c*64+lane],
// xor-butterfly offs 32,16,8,4,2,1, accumulate; then + b2[o].
__global__ __launch_bounds__(256) void k_h2(const float* __restrict__ spk,
                                            const float* __restrict__ W2,
                                            const float* __restrict__ b2,
                                            float* __restrict__ h2) {
#pragma clang fp contract(off)
    const int lane = threadIdx.x & 63;
    const int wave = threadIdx.x >> 6;
    size_t tb = (size_t)blockIdx.x * 4 + wave;    // t*B + b
    const float* row = spk + tb * HID;
    float s0 = 0.0f, s1 = 0.0f;
#pragma unroll
    for (int c = 0; c < 16; ++c) {
        float v  = row[c * 64 + lane];
        float r0 = v * W2[c * 64 + lane];
        float r1 = v * W2[HID + c * 64 + lane];
#pragma unroll
        for (int off = 32; off > 0; off >>= 1) {
            r0 += __shfl_xor(r0, off, 64);
            r1 += __shfl_xor(r1, off, 64);
        }
        s0 += r0;
        s1 += r1;
    }
    s0 += b2[0];
    s1 += b2[1];
    if (lane == 0)
        *reinterpret_cast<float2*>(h2 + tb * 2) = make_float2(s0, s1);
}

__global__ __launch_bounds__(256) void k_scan(const float* __restrict__ h2,
                                              float* __restrict__ outSpk,
                                              float* __restrict__ outMem2) {
#pragma clang fp contract(off)
    const int tid = threadIdx.x;                  // b*2 + o
    float mem = 0.0f;
    float cur[8], nxt[8];
#pragma unroll
    for (int k = 0; k < 8; ++k) cur[k] = h2[k * 256 + tid];
    for (int t0 = 0; t0 < TT; t0 += 8) {
#pragma unroll
        for (int k = 0; k < 8; ++k) {
            int tn = t0 + 8 + k;
            nxt[k] = (tn < TT) ? h2[tn * 256 + tid] : 0.0f;
        }
#pragma unroll
        for (int k = 0; k < 8; ++k) {
            float mm = 0.9f * mem;
            mm = mm + cur[k];
            float spk = (mm - 1.0f > 0.0f) ? 1.0f : 0.0f;
            mm = mm - spk;
            mem = mm;
            outSpk[(t0 + k) * 256 + tid] = spk;
        }
#pragma unroll
        for (int k = 0; k < 8; ++k) cur[k] = nxt[k];
    }
    outMem2[tid] = mem;
}

extern "C" void kernel_launch(void* const* d_in, const int* in_sizes, int n_in,
                              void* d_out, int out_size, void* d_ws, size_t ws_size,
                              hipStream_t stream) {
    const float* x  = (const float*)d_in[0];
    const float* W1 = (const float*)d_in[1];
    const float* b1 = (const float*)d_in[2];
    const float* W2 = (const float*)d_in[3];
    const float* b2 = (const float*)d_in[4];
    float* out = (float*)d_out;

    char* ws = (char*)d_ws;
    float*         W1T = (float*)(ws);                                 // 1 MB
    unsigned int*  cnt = (unsigned int*)(ws + (1 << 20));              // 512 KB
    unsigned char* idx = (unsigned char*)(ws + (1 << 20) + (1 << 19)); // 131072*slots

    // size the index lists to the workspace (fallback path covers overflow)
    size_t fixedB = (size_t)(1 << 20) + (1 << 19) + (1 << 20);
    size_t avail  = ws_size > fixedB ? ws_size - fixedB : 0;
    long   s      = (long)((avail / 131072) & ~(size_t)7);
    int slots = (int)(s > 96 ? 96 : (s < 8 ? 8 : s));

    float* h2 = (float*)(ws + (1 << 20) + (1 << 19) + (size_t)131072 * (size_t)slots); // 1 MB

    k_transpose<<<1024, 256, 0, stream>>>(W1, W1T);
    k_pack<<<131072, 256, 0, stream>>>(x, cnt, idx, slots);
    k_snn<<<256, 256, 0, stream>>>(W1T, cnt, idx, x, b1, out + OFF_HID, slots);
    k_h2<<<32768, 256, 0, stream>>>(out + OFF_HID, W2, b2, h2);
    k_scan<<<1, 256, 0, stream>>>(h2, out, out + OFF_MEM2);
}